// Round 7
// baseline (227.563 us; speedup 1.0000x reference)
//
#include <hip/hip_runtime.h>
#include <stdint.h>
#include <stddef.h>

// Attention_50886772523162: x[2,2048,1024] -> causal MHA (16 heads, hd=64) -> out
// dtype (fp32 vs bf16) detected at runtime; compute bf16 MFMA, fp32 accum.
// Pipeline: detect -> convert x -> transpose weights (Wq|Wkv fused) ->
//           QKV proj (one GEMM, global_load_lds staging) ->
//           swapped-QK^T flash attn (1-wave blocks, K direct-from-global,
//           V-only LDS dbuf, write-at-top, defer-max, setprio) -> O proj.
// NOTE: raw v_permlane32_swap_b32 inline asm caused NaN (R5) — blacklisted.

typedef __bf16 bf16;
typedef __bf16 bf16x8 __attribute__((ext_vector_type(8)));
typedef __bf16 bf16x4 __attribute__((ext_vector_type(4)));
typedef __bf16 bf16x2 __attribute__((ext_vector_type(2)));
typedef float  f32x4  __attribute__((ext_vector_type(4)));
typedef float  f32x16 __attribute__((ext_vector_type(16)));

#define NSEQ 2048
#define DM   1024
#define HD   64
#define QKVS 3072          // fused QKV row stride
#define LOG2E 1.44269504f

#define GLD16(g, l) __builtin_amdgcn_global_load_lds(                         \
    (const __attribute__((address_space(1))) void*)(g),                       \
    (__attribute__((address_space(3))) void*)(l), 16, 0, 0)

// ---------------- dtype detection ----------------
__global__ void detect_dtype(const uint32_t* __restrict__ x, int* __restrict__ flag) {
  __shared__ int cnt;
  if (threadIdx.x == 0) cnt = 0;
  __syncthreads();
  int c = 0;
  for (int i = threadIdx.x; i < 4096; i += 256) {
    uint32_t e = (x[i] >> 7) & 0xFF;
    if (e >= 110 && e <= 132) c++;
  }
  atomicAdd(&cnt, c);
  __syncthreads();
  if (threadIdx.x == 0) *flag = (cnt > 2048) ? 1 : 0;   // 1 = bf16 data
}

// ---------------- x -> canonical bf16 ----------------
__global__ __launch_bounds__(256) void convert_x(
    const void* __restrict__ in, bf16* __restrict__ out, int n,
    const int* __restrict__ flagp) {
  const int flag = *flagp;
  const int i = (blockIdx.x * 256 + threadIdx.x) * 8;
  if (i >= n) return;
  if (flag) {
    *(bf16x8*)(out + i) = *(const bf16x8*)((const bf16*)in + i);
  } else {
    const float* f = (const float*)in;
    bf16x8 v;
#pragma unroll
    for (int e = 0; e < 8; ++e) v[e] = (bf16)f[i + e];
    *(bf16x8*)(out + i) = v;
  }
}

// ---------------- weight transpose(+convert): in[K][N] -> out[N][K] ----------------
__global__ void transpose_conv(const void* __restrict__ in, bf16* __restrict__ out,
                               int K, int N, const int* __restrict__ flagp) {
  __shared__ bf16 tile[32][33];
  const int flag = *flagp;
  const int k0 = blockIdx.y * 32, n0 = blockIdx.x * 32;
  const int tx = threadIdx.x, ty = threadIdx.y;
  if (flag) {
    const bf16* p = (const bf16*)in;
#pragma unroll
    for (int i = ty; i < 32; i += 8)
      tile[i][tx] = p[(size_t)(k0 + i) * N + n0 + tx];
  } else {
    const float* p = (const float*)in;
#pragma unroll
    for (int i = ty; i < 32; i += 8)
      tile[i][tx] = (bf16)p[(size_t)(k0 + i) * N + n0 + tx];
  }
  __syncthreads();
#pragma unroll
  for (int i = ty; i < 32; i += 8)
    out[(size_t)(n0 + i) * K + k0 + tx] = tile[tx][i];
}

// ---------------- GEMM: C[M][N] = A[M][K] * Bt[N][K]^T ----------------
// 128x128 tile, BK=64, 4 waves (2x2), mfma_f32_16x16x32_bf16.
// Staging via global_load_lds (16B/lane, linear LDS dest, pre-swizzled source).
__global__ __launch_bounds__(256) void gemm_bt(
    const bf16* __restrict__ A, const bf16* __restrict__ Bt,
    void* __restrict__ C, int M, int N, int K, const int* flagp)
{
  __shared__ bf16 As[128][64];
  __shared__ bf16 Bs[128][64];
  const int tid  = threadIdx.x;
  const int wave = tid >> 6, lane = tid & 63;
  const int fr = lane & 15, fg = lane >> 4;
  const int m0 = blockIdx.y * 128, n0 = blockIdx.x * 128;
  const int wr = (wave >> 1) * 64, wc = (wave & 1) * 64;
  const int lrow = lane >> 3;                    // row within 8-row chunk
  const int lcol = 8 * ((lane & 7) ^ lrow);      // pre-swizzled source col (elems)

  f32x4 acc[4][4] = {};

  for (int kt = 0; kt < K; kt += 64) {
    __syncthreads();                              // protect prev-iter reads
#pragma unroll
    for (int p = 0; p < 4; ++p) {
      const int chunk = wave * 4 + p;             // 8 rows per chunk
      const int r = chunk * 8 + lrow;
      GLD16(A  + (size_t)(m0 + r) * K + kt + lcol, &As[chunk * 8][0]);
      GLD16(Bt + (size_t)(n0 + r) * K + kt + lcol, &Bs[chunk * 8][0]);
    }
    __syncthreads();                              // vmcnt(0) drain + barrier
#pragma unroll
    for (int s = 0; s < 2; ++s) {
      bf16x8 af[4], bfr[4];
#pragma unroll
      for (int i = 0; i < 4; ++i) {
        const int ar = wr + i * 16 + fr;
        af[i]  = *(const bf16x8*)((const char*)&As[ar][0] +
                   ((s * 64 + fg * 16) ^ ((ar & 7) << 4)));
        const int br = wc + i * 16 + fr;
        bfr[i] = *(const bf16x8*)((const char*)&Bs[br][0] +
                   ((s * 64 + fg * 16) ^ ((br & 7) << 4)));
      }
#pragma unroll
      for (int i = 0; i < 4; ++i)
#pragma unroll
        for (int j = 0; j < 4; ++j)
          acc[i][j] = __builtin_amdgcn_mfma_f32_16x16x32_bf16(
              af[i], bfr[j], acc[i][j], 0, 0, 0);
    }
  }
  const int crow = m0 + wr + fg * 4;
  const int ccol = n0 + wc + fr;
  const int as_bf16 = flagp ? *flagp : 1;
  if (as_bf16) {
    bf16* Cb = (bf16*)C;
#pragma unroll
    for (int i = 0; i < 4; ++i)
#pragma unroll
      for (int j = 0; j < 4; ++j)
#pragma unroll
        for (int r = 0; r < 4; ++r)
          Cb[(size_t)(crow + i * 16 + r) * N + ccol + j * 16] = (bf16)acc[i][j][r];
  } else {
    float* Cf = (float*)C;
#pragma unroll
    for (int i = 0; i < 4; ++i)
#pragma unroll
      for (int j = 0; j < 4; ++j)
#pragma unroll
        for (int r = 0; r < 4; ++r)
          Cf[(size_t)(crow + i * 16 + r) * N + ccol + j * 16] = acc[i][j][r];
  }
}

// ---------------- causal flash attention, 1-wave blocks ----------------
// QKV: [B*N][3072] rows = (Q | K | V), head col offset hi*64.
// Block = 1 wave (64 threads) owning 32 q-rows; grid 64 splits x 32 bh.
// S^T = mfma(K, Q): lane owns q-row (col=lane&31); softmax lane-local.
// O^T = mfma(V^T, P): output col also = q-row -> rescale/divide lane-local.
// K: A-fragments loaded DIRECTLY from global (L1/L2-resident, no LDS).
// V: transposed into LDS (double-buffered, XOR-swizzled), write-at-top.
static __device__ inline uint32_t pk2(float a, float b) {
  bf16x2 t; t[0] = (bf16)a; t[1] = (bf16)b;
  return __builtin_bit_cast(uint32_t, t);
}

__global__ __launch_bounds__(64) void attn_fwd(
    const bf16* __restrict__ QKV, bf16* __restrict__ O)
{
  __shared__ bf16 Vt[2][64][64];   // V^T tiles [d][kv], rows XOR-swizzled

  const int s  = gridDim.x - 1 - blockIdx.x;  // q-split 0..63, heavy first (LPT)
  const int bh = blockIdx.y;
  const int bi = bh >> 4, hi = bh & 15;
  const int lane = threadIdx.x;
  const int c = lane & 31, h = lane >> 5;

  const bf16* qptr = QKV + (size_t)bi * NSEQ * QKVS + hi * HD;
  const bf16* kptr = qptr + DM;
  const bf16* vptr = qptr + 2 * DM;

  const int q0 = s * 32;
  const int qrow = q0 + c;

  // Q fragments (B-operand): k = d = ks*16 + h*8 + e
  bf16x8 qf[4];
#pragma unroll
  for (int ks = 0; ks < 4; ++ks)
    qf[ks] = *(const bf16x8*)(qptr + (size_t)qrow * QKVS + ks * 16 + h * 8);

  f32x16 oacc[2] = {};          // O^T: col=q (lane-local), rows d spread
  float m = -1e30f, l = 0.f;

  // V staging geometry: lane covers 4 kv rows x 8 d cols, 2 passes over d
  const int kvg = (lane & 15) * 4;    // kv group base (4 rows)
  const int dg  = (lane >> 4) * 8;    // d group base (8 cols, +32 on pass 1)

  bf16x8 vpre[2][4];            // prefetch regs: [pass][row]

  const int ntil = s / 2 + 1;   // KV tiles of 64 covering kv <= q0+31

  // prologue: stage tile 0 -> Vt[0]; load tile 1 -> vpre
  {
#pragma unroll
    for (int p = 0; p < 2; ++p)
#pragma unroll
      for (int i = 0; i < 4; ++i)
        vpre[p][i] = *(const bf16x8*)(vptr + (size_t)(kvg + i) * QKVS + dg + p * 32);
#pragma unroll
    for (int p = 0; p < 2; ++p)
#pragma unroll
      for (int e = 0; e < 8; ++e) {
        const int d = dg + p * 32 + e;
        bf16x4 w; w[0] = vpre[p][0][e]; w[1] = vpre[p][1][e];
        w[2] = vpre[p][2][e]; w[3] = vpre[p][3][e];
        *(bf16x4*)((char*)&Vt[0][d][0] + ((2 * kvg) ^ ((d & 7) << 4))) = w;
      }
    if (ntil > 1) {
#pragma unroll
      for (int p = 0; p < 2; ++p)
#pragma unroll
        for (int i = 0; i < 4; ++i)
          vpre[p][i] = *(const bf16x8*)(vptr + (size_t)(64 + kvg + i) * QKVS + dg + p * 32);
    }
  }

  for (int t = 0; t < ntil; ++t) {
    const int cur = t & 1;
    const int j0 = t * 64;

    // publish tile t+1 (regs -> other buffer); single wave: no barrier needed
    if (t + 1 < ntil) {
#pragma unroll
      for (int p = 0; p < 2; ++p)
#pragma unroll
        for (int e = 0; e < 8; ++e) {
          const int d = dg + p * 32 + e;
          bf16x4 w; w[0] = vpre[p][0][e]; w[1] = vpre[p][1][e];
          w[2] = vpre[p][2][e]; w[3] = vpre[p][3][e];
          *(bf16x4*)((char*)&Vt[cur ^ 1][d][0] + ((2 * kvg) ^ ((d & 7) << 4))) = w;
        }
    }

    // K fragments for this tile: direct global loads (issued before V loads
    // so QK^T's waitcnt does not drain the V prefetch)
    bf16x8 kf[2][4];
#pragma unroll
    for (int blk = 0; blk < 2; ++blk)
#pragma unroll
      for (int ks = 0; ks < 4; ++ks)
        kf[blk][ks] = *(const bf16x8*)(kptr +
            (size_t)(j0 + blk * 32 + c) * QKVS + ks * 16 + h * 8);

    // issue tile t+2 V loads (drain during this tile's compute)
    if (t + 2 < ntil) {
      const int jn = j0 + 128;
#pragma unroll
      for (int p = 0; p < 2; ++p)
#pragma unroll
        for (int i = 0; i < 4; ++i)
          vpre[p][i] = *(const bf16x8*)(vptr + (size_t)(jn + kvg + i) * QKVS + dg + p * 32);
    }

    // last tile may have its upper 32-kv block fully masked for all 32 q-rows
    const int blkmax = (j0 + 32 <= q0 + 31) ? 2 : 1;

    // S^T: s[blk][r] = S[q = qrow][kv = j0 + 32*blk + (r&3)+8*(r>>2)+4*h]
    f32x16 sv[2];
    __builtin_amdgcn_s_setprio(1);
#pragma unroll
    for (int blk = 0; blk < 2; ++blk)
      if (blk < blkmax) {
        f32x16 a = {};
#pragma unroll
        for (int ks = 0; ks < 4; ++ks)
          a = __builtin_amdgcn_mfma_f32_32x32x16_bf16(kf[blk][ks], qf[ks], a, 0, 0, 0);
        sv[blk] = a;
      }
    __builtin_amdgcn_s_setprio(0);

    // causal mask (raw-S domain), last tile only
    if (j0 + 63 > q0) {
#pragma unroll
      for (int blk = 0; blk < 2; ++blk)
        if (blk < blkmax) {
          const int kvb = j0 + blk * 32 + 4 * h;
#pragma unroll
          for (int r = 0; r < 16; ++r) {
            const int kv = kvb + (r & 3) + 8 * (r >> 2);
            if (kv > qrow) sv[blk][r] = -4.0e8f;
          }
        }
    }

    // online softmax, lane-local; defer-max (T13, THR=8)
    float tmax = -3.0e38f;
#pragma unroll
    for (int blk = 0; blk < 2; ++blk)
      if (blk < blkmax)
#pragma unroll
        for (int r = 0; r < 16; ++r) tmax = fmaxf(tmax, sv[blk][r]);
    tmax = fmaxf(tmax, __shfl_xor(tmax, 32));
    const float pmax = tmax * 0.125f;
    if (!__all(pmax - m <= 8.0f)) {
      const float mnew  = fmaxf(m, pmax);
      const float alpha = __builtin_amdgcn_exp2f((m - mnew) * LOG2E);
      m = mnew;
      l *= alpha;
#pragma unroll
      for (int db = 0; db < 2; ++db)
#pragma unroll
        for (int r = 0; r < 16; ++r) oacc[db][r] *= alpha;
    }
    const float km = 0.125f * LOG2E, kb = -m * LOG2E;
    float sum = 0.f;
#pragma unroll
    for (int blk = 0; blk < 2; ++blk)
      if (blk < blkmax)
#pragma unroll
        for (int r = 0; r < 16; ++r) {
          const float p = __builtin_amdgcn_exp2f(__builtin_fmaf(sv[blk][r], km, kb));
          sv[blk][r] = p;
          sum += p;
        }
    sum += __shfl_xor(sum, 32);
    l += sum;

    // P redistribution (D-layout -> B-operand) + PV  [R4/R6-verified shfl form]
#pragma unroll
    for (int blk = 0; blk < 2; ++blk)
      if (blk < blkmax) {
        uint32_t w[8], xw[8];
#pragma unroll
        for (int g = 0; g < 4; ++g) {
          w[2 * g]     = pk2(sv[blk][4 * g],     sv[blk][4 * g + 1]);
          w[2 * g + 1] = pk2(sv[blk][4 * g + 2], sv[blk][4 * g + 3]);
        }
#pragma unroll
        for (int i = 0; i < 8; ++i)
          xw[i] = (uint32_t)__shfl_xor((int)w[i], 32);
#pragma unroll
        for (int ks = 0; ks < 2; ++ks) {
          union { uint32_t u[4]; bf16x8 v; } pf;
          pf.u[0] = h ? xw[4 * ks + 2] : w[4 * ks];
          pf.u[1] = h ? xw[4 * ks + 3] : w[4 * ks + 1];
          pf.u[2] = h ? w[4 * ks + 2]  : xw[4 * ks];
          pf.u[3] = h ? w[4 * ks + 3]  : xw[4 * ks + 1];
          __builtin_amdgcn_s_setprio(1);
#pragma unroll
          for (int db = 0; db < 2; ++db) {
            const int vrow = db * 32 + c;
            bf16x8 vf = *(const bf16x8*)((const char*)&Vt[cur][vrow][0] +
                         ((blk * 64 + ks * 32 + h * 16) ^ ((vrow & 7) << 4)));
            oacc[db] = __builtin_amdgcn_mfma_f32_32x32x16_bf16(vf, pf.v, oacc[db], 0, 0, 0);
          }
          __builtin_amdgcn_s_setprio(0);
        }
      }
  }

  // epilogue: O[q][d] = oacc^T / l   (all lane-local)
  const float linv = 1.f / l;
  bf16* obase = O + (size_t)bi * NSEQ * DM + (size_t)hi * HD + (size_t)qrow * DM;
#pragma unroll
  for (int db = 0; db < 2; ++db)
#pragma unroll
    for (int g = 0; g < 4; ++g) {
      bf16x4 ov;
#pragma unroll
      for (int j = 0; j < 4; ++j) ov[j] = (bf16)(oacc[db][4 * g + j] * linv);
      *(bf16x4*)(obase + db * 32 + 8 * g + 4 * h) = ov;
    }
}

// ---------------- launch ----------------
extern "C" void kernel_launch(void* const* d_in, const int* in_sizes, int n_in,
                              void* d_out, int out_size, void* d_ws, size_t ws_size,
                              hipStream_t stream) {
  const void* x   = d_in[0];   // [2,2048,1024]
  const void* Wq  = d_in[1];   // [1024,1024]
  const void* Wkv = d_in[2];   // [1024,2048]
  const void* Wo  = d_in[3];   // [1024,1024]

  char* ws = (char*)d_ws;
  int*  flag   = (int*)ws;                                      //   4 KiB
  bf16* xb     = (bf16*)(ws + (4ull << 10));                    //   8 MiB
  bf16* WqkvT  = (bf16*)(ws + (4ull << 10) + (8ull  << 20));    //   6 MiB [3072][1024]
  bf16* WoT    = (bf16*)(ws + (4ull << 10) + (14ull << 20));    //   2 MiB [1024][1024]
  bf16* QKVb   = (bf16*)(ws + (4ull << 10) + (16ull << 20));    //  24 MiB [4096][3072]
  bf16* AOb    = xb;  // x dead after projection; reuse

  detect_dtype<<<1, 256, 0, stream>>>((const uint32_t*)x, flag);
  convert_x<<<4194304 / 8 / 256, 256, 0, stream>>>(x, xb, 4194304, flag);

  const dim3 tb(32, 8);
  transpose_conv<<<dim3(1024 / 32, 1024 / 32), tb, 0, stream>>>(Wq,  WqkvT,                1024, 1024, flag);
  transpose_conv<<<dim3(2048 / 32, 1024 / 32), tb, 0, stream>>>(Wkv, WqkvT + 1024 * 1024,  1024, 2048, flag);
  transpose_conv<<<dim3(1024 / 32, 1024 / 32), tb, 0, stream>>>(Wo,  WoT,                  1024, 1024, flag);

  // fused QKV projection: x @ [Wq | Wkv]
  gemm_bt<<<dim3(3072 / 128, 4096 / 128), 256, 0, stream>>>(xb, WqkvT, QKVb, 4096, 3072, 1024, nullptr);

  attn_fwd<<<dim3(64, 32), 64, 0, stream>>>(QKVb, AOb);

  gemm_bt<<<dim3(1024 / 128, 4096 / 128), 256, 0, stream>>>(AOb, WoT, d_out, 4096, 1024, 1024, flag);
}

// Round 8
// 165.130 us; speedup vs baseline: 1.3781x; 1.3781x over previous
//
#include <hip/hip_runtime.h>
#include <stdint.h>
#include <stddef.h>

// Attention_50886772523162: x[2,2048,1024] -> causal MHA (16 heads, hd=64) -> out
// dtype (fp32 vs bf16) detected at runtime; compute bf16 MFMA, fp32 accum.
// Pipeline: detect -> convert x -> transpose weights (Wq|Wkv fused) ->
//           QKV proj (one GEMM, global_load_lds staging) ->
//           swapped-QK^T flash attn (2-wave blocks, K+V LDS dbuf,
//           write-at-top, defer-max, setprio) -> O proj.
// NOTE: raw v_permlane32_swap_b32 inline asm caused NaN (R5) — blacklisted.
// NOTE: K direct-from-global (R7) regressed 2x: 64-lane scattered loads cost
//       ~1 cycle/cache-line in the addressing pipe; keep cooperative staging.

typedef __bf16 bf16;
typedef __bf16 bf16x8 __attribute__((ext_vector_type(8)));
typedef __bf16 bf16x4 __attribute__((ext_vector_type(4)));
typedef __bf16 bf16x2 __attribute__((ext_vector_type(2)));
typedef float  f32x4  __attribute__((ext_vector_type(4)));
typedef float  f32x16 __attribute__((ext_vector_type(16)));

#define NSEQ 2048
#define DM   1024
#define HD   64
#define QKVS 3072          // fused QKV row stride
#define LOG2E 1.44269504f

#define GLD16(g, l) __builtin_amdgcn_global_load_lds(                         \
    (const __attribute__((address_space(1))) void*)(g),                       \
    (__attribute__((address_space(3))) void*)(l), 16, 0, 0)

// ---------------- dtype detection ----------------
__global__ void detect_dtype(const uint32_t* __restrict__ x, int* __restrict__ flag) {
  __shared__ int cnt;
  if (threadIdx.x == 0) cnt = 0;
  __syncthreads();
  int c = 0;
  for (int i = threadIdx.x; i < 4096; i += 256) {
    uint32_t e = (x[i] >> 7) & 0xFF;
    if (e >= 110 && e <= 132) c++;
  }
  atomicAdd(&cnt, c);
  __syncthreads();
  if (threadIdx.x == 0) *flag = (cnt > 2048) ? 1 : 0;   // 1 = bf16 data
}

// ---------------- x -> canonical bf16 ----------------
__global__ __launch_bounds__(256) void convert_x(
    const void* __restrict__ in, bf16* __restrict__ out, int n,
    const int* __restrict__ flagp) {
  const int flag = *flagp;
  const int i = (blockIdx.x * 256 + threadIdx.x) * 8;
  if (i >= n) return;
  if (flag) {
    *(bf16x8*)(out + i) = *(const bf16x8*)((const bf16*)in + i);
  } else {
    const float* f = (const float*)in;
    bf16x8 v;
#pragma unroll
    for (int e = 0; e < 8; ++e) v[e] = (bf16)f[i + e];
    *(bf16x8*)(out + i) = v;
  }
}

// ---------------- weight transpose(+convert): in[K][N] -> out[N][K] ----------------
__global__ void transpose_conv(const void* __restrict__ in, bf16* __restrict__ out,
                               int K, int N, const int* __restrict__ flagp) {
  __shared__ bf16 tile[32][33];
  const int flag = *flagp;
  const int k0 = blockIdx.y * 32, n0 = blockIdx.x * 32;
  const int tx = threadIdx.x, ty = threadIdx.y;
  if (flag) {
    const bf16* p = (const bf16*)in;
#pragma unroll
    for (int i = ty; i < 32; i += 8)
      tile[i][tx] = p[(size_t)(k0 + i) * N + n0 + tx];
  } else {
    const float* p = (const float*)in;
#pragma unroll
    for (int i = ty; i < 32; i += 8)
      tile[i][tx] = (bf16)p[(size_t)(k0 + i) * N + n0 + tx];
  }
  __syncthreads();
#pragma unroll
  for (int i = ty; i < 32; i += 8)
    out[(size_t)(n0 + i) * K + k0 + tx] = tile[tx][i];
}

// ---------------- GEMM: C[M][N] = A[M][K] * Bt[N][K]^T ----------------
// 128x128 tile, BK=64, 4 waves (2x2), mfma_f32_16x16x32_bf16.
// Staging via global_load_lds (16B/lane, linear LDS dest, pre-swizzled source).
__global__ __launch_bounds__(256) void gemm_bt(
    const bf16* __restrict__ A, const bf16* __restrict__ Bt,
    void* __restrict__ C, int M, int N, int K, const int* flagp)
{
  __shared__ bf16 As[128][64];
  __shared__ bf16 Bs[128][64];
  const int tid  = threadIdx.x;
  const int wave = tid >> 6, lane = tid & 63;
  const int fr = lane & 15, fg = lane >> 4;
  const int m0 = blockIdx.y * 128, n0 = blockIdx.x * 128;
  const int wr = (wave >> 1) * 64, wc = (wave & 1) * 64;
  const int lrow = lane >> 3;                    // row within 8-row chunk
  const int lcol = 8 * ((lane & 7) ^ lrow);      // pre-swizzled source col (elems)

  f32x4 acc[4][4] = {};

  for (int kt = 0; kt < K; kt += 64) {
    __syncthreads();                              // protect prev-iter reads
#pragma unroll
    for (int p = 0; p < 4; ++p) {
      const int chunk = wave * 4 + p;             // 8 rows per chunk
      const int r = chunk * 8 + lrow;
      GLD16(A  + (size_t)(m0 + r) * K + kt + lcol, &As[chunk * 8][0]);
      GLD16(Bt + (size_t)(n0 + r) * K + kt + lcol, &Bs[chunk * 8][0]);
    }
    __syncthreads();                              // vmcnt(0) drain + barrier
#pragma unroll
    for (int s = 0; s < 2; ++s) {
      bf16x8 af[4], bfr[4];
#pragma unroll
      for (int i = 0; i < 4; ++i) {
        const int ar = wr + i * 16 + fr;
        af[i]  = *(const bf16x8*)((const char*)&As[ar][0] +
                   ((s * 64 + fg * 16) ^ ((ar & 7) << 4)));
        const int br = wc + i * 16 + fr;
        bfr[i] = *(const bf16x8*)((const char*)&Bs[br][0] +
                   ((s * 64 + fg * 16) ^ ((br & 7) << 4)));
      }
#pragma unroll
      for (int i = 0; i < 4; ++i)
#pragma unroll
        for (int j = 0; j < 4; ++j)
          acc[i][j] = __builtin_amdgcn_mfma_f32_16x16x32_bf16(
              af[i], bfr[j], acc[i][j], 0, 0, 0);
    }
  }
  const int crow = m0 + wr + fg * 4;
  const int ccol = n0 + wc + fr;
  const int as_bf16 = flagp ? *flagp : 1;
  if (as_bf16) {
    bf16* Cb = (bf16*)C;
#pragma unroll
    for (int i = 0; i < 4; ++i)
#pragma unroll
      for (int j = 0; j < 4; ++j)
#pragma unroll
        for (int r = 0; r < 4; ++r)
          Cb[(size_t)(crow + i * 16 + r) * N + ccol + j * 16] = (bf16)acc[i][j][r];
  } else {
    float* Cf = (float*)C;
#pragma unroll
    for (int i = 0; i < 4; ++i)
#pragma unroll
      for (int j = 0; j < 4; ++j)
#pragma unroll
        for (int r = 0; r < 4; ++r)
          Cf[(size_t)(crow + i * 16 + r) * N + ccol + j * 16] = acc[i][j][r];
  }
}

// ---------------- causal flash attention, 2-wave blocks ----------------
// QKV: [B*N][3072] rows = (Q | K | V), head col offset hi*64.
// Block = 2 waves (128 threads), 64 q-rows; grid 32 qtiles x 32 bh = 1024.
// LDS 32 KiB -> 5 blocks/CU = 10 waves/CU (2.5x the R6 grid-limited ceiling).
// S^T = mfma(K, Q): lane owns q-row (col=lane&31); softmax lane-local.
// O^T = mfma(V^T, P): output col also = q-row -> rescale/divide lane-local.
// Schedule per tile t: [publish regs(t+1)->LDS | issue loads(t+2) | compute(t)]
// -> barrier (R6-verified).
static __device__ inline uint32_t pk2(float a, float b) {
  bf16x2 t; t[0] = (bf16)a; t[1] = (bf16)b;
  return __builtin_bit_cast(uint32_t, t);
}

__global__ __launch_bounds__(128) void attn_fwd(
    const bf16* __restrict__ QKV, bf16* __restrict__ O)
{
  __shared__ bf16 Ks[2][64][64];   // K tiles [kv][d], rows XOR-swizzled
  __shared__ bf16 Vt[2][64][64];   // V^T tiles [d][kv], rows XOR-swizzled

  const int qt = gridDim.x - 1 - blockIdx.x;  // q-tile 0..31, heavy first (LPT)
  const int bh = blockIdx.y;
  const int bi = bh >> 4, hi = bh & 15;
  const int tid = threadIdx.x, wave = tid >> 6, lane = tid & 63;
  const int c = lane & 31, h = lane >> 5;

  const bf16* qptr = QKV + (size_t)bi * NSEQ * QKVS + hi * HD;
  const bf16* kptr = qptr + DM;
  const bf16* vptr = qptr + 2 * DM;

  const int q0w  = qt * 64 + wave * 32;
  const int qrow = q0w + c;

  // Q fragments (B-operand): k = d = ks*16 + h*8 + e
  bf16x8 qf[4];
#pragma unroll
  for (int ks = 0; ks < 4; ++ks)
    qf[ks] = *(const bf16x8*)(qptr + (size_t)qrow * QKVS + ks * 16 + h * 8);

  f32x16 oacc[2] = {};          // O^T: col=q (lane-local), rows d spread
  float m = -1e30f, l = 0.f;

  // K staging: 128 threads cover 16 rows x 8 chunks per pass, 4 passes
  const int srow = tid >> 3, sch = tid & 7;
  const int koff = (sch * 16) ^ ((srow & 7) << 4);   // (row+16p)&7 == row&7
  // V staging: thread covers 4 kv rows x 8 d cols (64x64 in one pass)
  const int kvg = (tid & 15) * 4, dg = (tid >> 4) * 8;

  bf16x8 kpre[4], vpre[4];      // prefetch regs (loaded t-1, published top of t+1)

  const int ntil = qt + 1;

  // prologue: tile0 -> LDS buf0 directly; tile1 -> regs
  {
#pragma unroll
    for (int p = 0; p < 4; ++p)
      kpre[p] = *(const bf16x8*)(kptr + (size_t)(srow + 16 * p) * QKVS + sch * 8);
#pragma unroll
    for (int i = 0; i < 4; ++i)
      vpre[i] = *(const bf16x8*)(vptr + (size_t)(kvg + i) * QKVS + dg);
#pragma unroll
    for (int p = 0; p < 4; ++p)
      *(bf16x8*)((char*)&Ks[0][srow + 16 * p][0] + koff) = kpre[p];
#pragma unroll
    for (int e = 0; e < 8; ++e) {
      const int d = dg + e;
      bf16x4 w; w[0] = vpre[0][e]; w[1] = vpre[1][e];
      w[2] = vpre[2][e]; w[3] = vpre[3][e];
      *(bf16x4*)((char*)&Vt[0][d][0] + ((2 * kvg) ^ ((d & 7) << 4))) = w;
    }
    if (ntil > 1) {
#pragma unroll
      for (int p = 0; p < 4; ++p)
        kpre[p] = *(const bf16x8*)(kptr + (size_t)(64 + srow + 16 * p) * QKVS + sch * 8);
#pragma unroll
      for (int i = 0; i < 4; ++i)
        vpre[i] = *(const bf16x8*)(vptr + (size_t)(64 + kvg + i) * QKVS + dg);
    }
  }
  __syncthreads();

  for (int t = 0; t < ntil; ++t) {
    const int cur = t & 1;
    const int j0 = t * 64;

    // top: publish tile t+1 into the other buffer (its readers finished
    // before the barrier that ended iter t-1)
    if (t + 1 < ntil) {
      const int nb = cur ^ 1;
#pragma unroll
      for (int p = 0; p < 4; ++p)
        *(bf16x8*)((char*)&Ks[nb][srow + 16 * p][0] + koff) = kpre[p];
#pragma unroll
      for (int e = 0; e < 8; ++e) {
        const int d = dg + e;
        bf16x4 w; w[0] = vpre[0][e]; w[1] = vpre[1][e];
        w[2] = vpre[2][e]; w[3] = vpre[3][e];
        *(bf16x4*)((char*)&Vt[nb][d][0] + ((2 * kvg) ^ ((d & 7) << 4))) = w;
      }
    }
    // issue tile t+2 loads (land during next iteration's compute)
    if (t + 2 < ntil) {
      const int jn = j0 + 128;
#pragma unroll
      for (int p = 0; p < 4; ++p)
        kpre[p] = *(const bf16x8*)(kptr + (size_t)(jn + srow + 16 * p) * QKVS + sch * 8);
#pragma unroll
      for (int i = 0; i < 4; ++i)
        vpre[i] = *(const bf16x8*)(vptr + (size_t)(jn + kvg + i) * QKVS + dg);
    }

    // last tile: wave 0's upper 32-kv block is fully masked -> skip it
    const int blkmax = (j0 + 32 <= q0w + 31) ? 2 : 1;

    // S^T: sv[blk][r] = S[q = qrow][kv = j0 + 32*blk + (r&3)+8*(r>>2)+4*h]
    f32x16 sv[2];
    __builtin_amdgcn_s_setprio(1);
#pragma unroll
    for (int blk = 0; blk < 2; ++blk)
      if (blk < blkmax) {
        f32x16 a = {};
#pragma unroll
        for (int ks = 0; ks < 4; ++ks) {
          const int krow = blk * 32 + c;
          bf16x8 kf = *(const bf16x8*)((const char*)&Ks[cur][krow][0] +
                       ((ks * 32 + h * 16) ^ ((krow & 7) << 4)));
          a = __builtin_amdgcn_mfma_f32_32x32x16_bf16(kf, qf[ks], a, 0, 0, 0);
        }
        sv[blk] = a;
      }
    __builtin_amdgcn_s_setprio(0);

    // causal mask (raw-S domain), final tile only
    if (j0 + 63 > q0w) {
#pragma unroll
      for (int blk = 0; blk < 2; ++blk)
        if (blk < blkmax) {
          const int kvb = j0 + blk * 32 + 4 * h;
#pragma unroll
          for (int r = 0; r < 16; ++r) {
            const int kv = kvb + (r & 3) + 8 * (r >> 2);
            if (kv > qrow) sv[blk][r] = -4.0e8f;
          }
        }
    }

    // online softmax, lane-local; defer-max (T13, THR=8)
    float tmax = -3.0e38f;
#pragma unroll
    for (int blk = 0; blk < 2; ++blk)
      if (blk < blkmax)
#pragma unroll
        for (int r = 0; r < 16; ++r) tmax = fmaxf(tmax, sv[blk][r]);
    tmax = fmaxf(tmax, __shfl_xor(tmax, 32));
    const float pmax = tmax * 0.125f;
    if (!__all(pmax - m <= 8.0f)) {
      const float mnew  = fmaxf(m, pmax);
      const float alpha = __builtin_amdgcn_exp2f((m - mnew) * LOG2E);
      m = mnew;
      l *= alpha;
#pragma unroll
      for (int db = 0; db < 2; ++db)
#pragma unroll
        for (int r = 0; r < 16; ++r) oacc[db][r] *= alpha;
    }
    const float km = 0.125f * LOG2E, kb = -m * LOG2E;
    float sum = 0.f;
#pragma unroll
    for (int blk = 0; blk < 2; ++blk)
      if (blk < blkmax)
#pragma unroll
        for (int r = 0; r < 16; ++r) {
          const float p = __builtin_amdgcn_exp2f(__builtin_fmaf(sv[blk][r], km, kb));
          sv[blk][r] = p;
          sum += p;
        }
    sum += __shfl_xor(sum, 32);
    l += sum;

    // P redistribution (D-layout -> B-operand) + PV  [R4/R6-verified shfl form]
#pragma unroll
    for (int blk = 0; blk < 2; ++blk)
      if (blk < blkmax) {
        uint32_t w[8], xw[8];
#pragma unroll
        for (int g = 0; g < 4; ++g) {
          w[2 * g]     = pk2(sv[blk][4 * g],     sv[blk][4 * g + 1]);
          w[2 * g + 1] = pk2(sv[blk][4 * g + 2], sv[blk][4 * g + 3]);
        }
#pragma unroll
        for (int i = 0; i < 8; ++i)
          xw[i] = (uint32_t)__shfl_xor((int)w[i], 32);
#pragma unroll
        for (int ks = 0; ks < 2; ++ks) {
          union { uint32_t u[4]; bf16x8 v; } pf;
          pf.u[0] = h ? xw[4 * ks + 2] : w[4 * ks];
          pf.u[1] = h ? xw[4 * ks + 3] : w[4 * ks + 1];
          pf.u[2] = h ? w[4 * ks + 2]  : xw[4 * ks];
          pf.u[3] = h ? w[4 * ks + 3]  : xw[4 * ks + 1];
          __builtin_amdgcn_s_setprio(1);
#pragma unroll
          for (int db = 0; db < 2; ++db) {
            const int vrow = db * 32 + c;
            bf16x8 vf = *(const bf16x8*)((const char*)&Vt[cur][vrow][0] +
                         ((blk * 64 + ks * 32 + h * 16) ^ ((vrow & 7) << 4)));
            oacc[db] = __builtin_amdgcn_mfma_f32_32x32x16_bf16(vf, pf.v, oacc[db], 0, 0, 0);
          }
          __builtin_amdgcn_s_setprio(0);
        }
      }

    __syncthreads();              // single barrier per tile
  }

  // epilogue: O[q][d] = oacc^T / l   (all lane-local)
  const float linv = 1.f / l;
  bf16* obase = O + (size_t)bi * NSEQ * DM + (size_t)hi * HD + (size_t)qrow * DM;
#pragma unroll
  for (int db = 0; db < 2; ++db)
#pragma unroll
    for (int g = 0; g < 4; ++g) {
      bf16x4 ov;
#pragma unroll
      for (int j = 0; j < 4; ++j) ov[j] = (bf16)(oacc[db][4 * g + j] * linv);
      *(bf16x4*)(obase + db * 32 + 8 * g + 4 * h) = ov;
    }
}

// ---------------- launch ----------------
extern "C" void kernel_launch(void* const* d_in, const int* in_sizes, int n_in,
                              void* d_out, int out_size, void* d_ws, size_t ws_size,
                              hipStream_t stream) {
  const void* x   = d_in[0];   // [2,2048,1024]
  const void* Wq  = d_in[1];   // [1024,1024]
  const void* Wkv = d_in[2];   // [1024,2048]
  const void* Wo  = d_in[3];   // [1024,1024]

  char* ws = (char*)d_ws;
  int*  flag   = (int*)ws;                                      //   4 KiB
  bf16* xb     = (bf16*)(ws + (4ull << 10));                    //   8 MiB
  bf16* WqkvT  = (bf16*)(ws + (4ull << 10) + (8ull  << 20));    //   6 MiB [3072][1024]
  bf16* WoT    = (bf16*)(ws + (4ull << 10) + (14ull << 20));    //   2 MiB [1024][1024]
  bf16* QKVb   = (bf16*)(ws + (4ull << 10) + (16ull << 20));    //  24 MiB [4096][3072]
  bf16* AOb    = xb;  // x dead after projection; reuse

  detect_dtype<<<1, 256, 0, stream>>>((const uint32_t*)x, flag);
  convert_x<<<4194304 / 8 / 256, 256, 0, stream>>>(x, xb, 4194304, flag);

  const dim3 tb(32, 8);
  transpose_conv<<<dim3(1024 / 32, 1024 / 32), tb, 0, stream>>>(Wq,  WqkvT,                1024, 1024, flag);
  transpose_conv<<<dim3(2048 / 32, 1024 / 32), tb, 0, stream>>>(Wkv, WqkvT + 1024 * 1024,  1024, 2048, flag);
  transpose_conv<<<dim3(1024 / 32, 1024 / 32), tb, 0, stream>>>(Wo,  WoT,                  1024, 1024, flag);

  // fused QKV projection: x @ [Wq | Wkv]
  gemm_bt<<<dim3(3072 / 128, 4096 / 128), 256, 0, stream>>>(xb, WqkvT, QKVb, 4096, 3072, 1024, nullptr);

  attn_fwd<<<dim3(32, 32), 128, 0, stream>>>(QKVb, AOb);

  gemm_bt<<<dim3(1024 / 128, 4096 / 128), 256, 0, stream>>>(AOb, WoT, d_out, 4096, 1024, 1024, flag);
}

// Round 9
// 149.174 us; speedup vs baseline: 1.5255x; 1.1070x over previous
//
#include <hip/hip_runtime.h>
#include <stdint.h>
#include <stddef.h>

// Attention_50886772523162: x[2,2048,1024] -> causal MHA (16 heads, hd=64) -> out
// dtype (fp32 vs bf16) detected at runtime; compute bf16 MFMA, fp32 accum.
// Pipeline: detect -> convert x -> transpose weights (Wq|Wkv fused) ->
//           QKV proj (one GEMM, global_load_lds staging) ->
//           swapped-QK^T flash attn (complementary-strip balanced waves,
//           K+V LDS dbuf, write-at-top, defer-max, setprio) -> O proj.
// NOTE: raw v_permlane32_swap_b32 inline asm caused NaN (R5) — blacklisted.
// NOTE: K direct-from-global (R7) regressed 2x — keep cooperative staging.
// NOTE: R8 lesson: with grid <= resident capacity there is NO backfill;
//       causal imbalance => duration = longest block. Fix = equal work per
//       wave via complementary strips (sA, 63-sA): 33 tile-units for every
//       wave in the machine.

typedef __bf16 bf16;
typedef __bf16 bf16x8 __attribute__((ext_vector_type(8)));
typedef __bf16 bf16x4 __attribute__((ext_vector_type(4)));
typedef __bf16 bf16x2 __attribute__((ext_vector_type(2)));
typedef float  f32x4  __attribute__((ext_vector_type(4)));
typedef float  f32x16 __attribute__((ext_vector_type(16)));

#define NSEQ 2048
#define DM   1024
#define HD   64
#define QKVS 3072          // fused QKV row stride
#define LOG2E 1.44269504f

#define GLD16(g, l) __builtin_amdgcn_global_load_lds(                         \
    (const __attribute__((address_space(1))) void*)(g),                       \
    (__attribute__((address_space(3))) void*)(l), 16, 0, 0)

// ---------------- dtype detection ----------------
__global__ void detect_dtype(const uint32_t* __restrict__ x, int* __restrict__ flag) {
  __shared__ int cnt;
  if (threadIdx.x == 0) cnt = 0;
  __syncthreads();
  int c = 0;
  for (int i = threadIdx.x; i < 4096; i += 256) {
    uint32_t e = (x[i] >> 7) & 0xFF;
    if (e >= 110 && e <= 132) c++;
  }
  atomicAdd(&cnt, c);
  __syncthreads();
  if (threadIdx.x == 0) *flag = (cnt > 2048) ? 1 : 0;   // 1 = bf16 data
}

// ---------------- x -> canonical bf16 ----------------
__global__ __launch_bounds__(256) void convert_x(
    const void* __restrict__ in, bf16* __restrict__ out, int n,
    const int* __restrict__ flagp) {
  const int flag = *flagp;
  const int i = (blockIdx.x * 256 + threadIdx.x) * 8;
  if (i >= n) return;
  if (flag) {
    *(bf16x8*)(out + i) = *(const bf16x8*)((const bf16*)in + i);
  } else {
    const float* f = (const float*)in;
    bf16x8 v;
#pragma unroll
    for (int e = 0; e < 8; ++e) v[e] = (bf16)f[i + e];
    *(bf16x8*)(out + i) = v;
  }
}

// ---------------- weight transpose(+convert): in[K][N] -> out[N][K] ----------------
__global__ void transpose_conv(const void* __restrict__ in, bf16* __restrict__ out,
                               int K, int N, const int* __restrict__ flagp) {
  __shared__ bf16 tile[32][33];
  const int flag = *flagp;
  const int k0 = blockIdx.y * 32, n0 = blockIdx.x * 32;
  const int tx = threadIdx.x, ty = threadIdx.y;
  if (flag) {
    const bf16* p = (const bf16*)in;
#pragma unroll
    for (int i = ty; i < 32; i += 8)
      tile[i][tx] = p[(size_t)(k0 + i) * N + n0 + tx];
  } else {
    const float* p = (const float*)in;
#pragma unroll
    for (int i = ty; i < 32; i += 8)
      tile[i][tx] = (bf16)p[(size_t)(k0 + i) * N + n0 + tx];
  }
  __syncthreads();
#pragma unroll
  for (int i = ty; i < 32; i += 8)
    out[(size_t)(n0 + i) * K + k0 + tx] = tile[tx][i];
}

// ---------------- GEMM: C[M][N] = A[M][K] * Bt[N][K]^T ----------------
// 128x128 tile, BK=64, 4 waves (2x2), mfma_f32_16x16x32_bf16.
// Staging via global_load_lds (16B/lane, linear LDS dest, pre-swizzled source).
__global__ __launch_bounds__(256) void gemm_bt(
    const bf16* __restrict__ A, const bf16* __restrict__ Bt,
    void* __restrict__ C, int M, int N, int K, const int* flagp)
{
  __shared__ bf16 As[128][64];
  __shared__ bf16 Bs[128][64];
  const int tid  = threadIdx.x;
  const int wave = tid >> 6, lane = tid & 63;
  const int fr = lane & 15, fg = lane >> 4;
  const int m0 = blockIdx.y * 128, n0 = blockIdx.x * 128;
  const int wr = (wave >> 1) * 64, wc = (wave & 1) * 64;
  const int lrow = lane >> 3;                    // row within 8-row chunk
  const int lcol = 8 * ((lane & 7) ^ lrow);      // pre-swizzled source col (elems)

  f32x4 acc[4][4] = {};

  for (int kt = 0; kt < K; kt += 64) {
    __syncthreads();                              // protect prev-iter reads
#pragma unroll
    for (int p = 0; p < 4; ++p) {
      const int chunk = wave * 4 + p;             // 8 rows per chunk
      const int r = chunk * 8 + lrow;
      GLD16(A  + (size_t)(m0 + r) * K + kt + lcol, &As[chunk * 8][0]);
      GLD16(Bt + (size_t)(n0 + r) * K + kt + lcol, &Bs[chunk * 8][0]);
    }
    __syncthreads();                              // vmcnt(0) drain + barrier
#pragma unroll
    for (int s = 0; s < 2; ++s) {
      bf16x8 af[4], bfr[4];
#pragma unroll
      for (int i = 0; i < 4; ++i) {
        const int ar = wr + i * 16 + fr;
        af[i]  = *(const bf16x8*)((const char*)&As[ar][0] +
                   ((s * 64 + fg * 16) ^ ((ar & 7) << 4)));
        const int br = wc + i * 16 + fr;
        bfr[i] = *(const bf16x8*)((const char*)&Bs[br][0] +
                   ((s * 64 + fg * 16) ^ ((br & 7) << 4)));
      }
#pragma unroll
      for (int i = 0; i < 4; ++i)
#pragma unroll
        for (int j = 0; j < 4; ++j)
          acc[i][j] = __builtin_amdgcn_mfma_f32_16x16x32_bf16(
              af[i], bfr[j], acc[i][j], 0, 0, 0);
    }
  }
  const int crow = m0 + wr + fg * 4;
  const int ccol = n0 + wc + fr;
  const int as_bf16 = flagp ? *flagp : 1;
  if (as_bf16) {
    bf16* Cb = (bf16*)C;
#pragma unroll
    for (int i = 0; i < 4; ++i)
#pragma unroll
      for (int j = 0; j < 4; ++j)
#pragma unroll
        for (int r = 0; r < 4; ++r)
          Cb[(size_t)(crow + i * 16 + r) * N + ccol + j * 16] = (bf16)acc[i][j][r];
  } else {
    float* Cf = (float*)C;
#pragma unroll
    for (int i = 0; i < 4; ++i)
#pragma unroll
      for (int j = 0; j < 4; ++j)
#pragma unroll
        for (int r = 0; r < 4; ++r)
          Cf[(size_t)(crow + i * 16 + r) * N + ccol + j * 16] = acc[i][j][r];
  }
}

// ---------------- causal flash attention, balanced strips ----------------
// QKV: [B*N][3072] rows = (Q | K | V), head col offset hi*64.
// Block = 2 waves (128 threads); grid 16 pairs x 32 bh = 512 blocks.
// Wave owns strips sA = 2*pair+wave and sB = 63-sA (32 q-rows each).
// Per tile: strip B always computes; strip A while t <= pair. Work per wave
// = (32-pair) + (pair+1) = 33 tile-units, uniform machine-wide.
// S^T = mfma(K, Q): lane owns q-row; softmax lane-local (R4/R6-verified core).
static __device__ inline uint32_t pk2(float a, float b) {
  bf16x2 t; t[0] = (bf16)a; t[1] = (bf16)b;
  return __builtin_bit_cast(uint32_t, t);
}

// One strip x one KV tile: QK^T -> mask -> online softmax -> repack -> PV.
// Verbatim R8-verified compute core, parameterized by strip state.
static __device__ __forceinline__ void strip_tile(
    const bf16 (&Ksb)[64][64], const bf16 (&Vtb)[64][64],
    const bf16x8 (&qf)[4], f32x16 (&oacc)[2], float& m, float& l,
    const int j0, const int q0, const int c, const int h)
{
  const int qrow = q0 + c;
  const int blkmax = (j0 + 32 <= q0 + 31) ? 2 : 1;

  f32x16 sv[2];
  __builtin_amdgcn_s_setprio(1);
#pragma unroll
  for (int blk = 0; blk < 2; ++blk)
    if (blk < blkmax) {
      f32x16 a = {};
#pragma unroll
      for (int ks = 0; ks < 4; ++ks) {
        const int krow = blk * 32 + c;
        bf16x8 kf = *(const bf16x8*)((const char*)&Ksb[krow][0] +
                     ((ks * 32 + h * 16) ^ ((krow & 7) << 4)));
        a = __builtin_amdgcn_mfma_f32_32x32x16_bf16(kf, qf[ks], a, 0, 0, 0);
      }
      sv[blk] = a;
    }
  __builtin_amdgcn_s_setprio(0);

  if (j0 + 63 > q0) {                       // causal mask (raw-S domain)
#pragma unroll
    for (int blk = 0; blk < 2; ++blk)
      if (blk < blkmax) {
        const int kvb = j0 + blk * 32 + 4 * h;
#pragma unroll
        for (int r = 0; r < 16; ++r) {
          const int kv = kvb + (r & 3) + 8 * (r >> 2);
          if (kv > qrow) sv[blk][r] = -4.0e8f;
        }
      }
  }

  // online softmax, lane-local; defer-max (T13, THR=8)
  float tmax = -3.0e38f;
#pragma unroll
  for (int blk = 0; blk < 2; ++blk)
    if (blk < blkmax)
#pragma unroll
      for (int r = 0; r < 16; ++r) tmax = fmaxf(tmax, sv[blk][r]);
  tmax = fmaxf(tmax, __shfl_xor(tmax, 32));
  const float pmax = tmax * 0.125f;
  if (!__all(pmax - m <= 8.0f)) {
    const float mnew  = fmaxf(m, pmax);
    const float alpha = __builtin_amdgcn_exp2f((m - mnew) * LOG2E);
    m = mnew;
    l *= alpha;
#pragma unroll
    for (int db = 0; db < 2; ++db)
#pragma unroll
      for (int r = 0; r < 16; ++r) oacc[db][r] *= alpha;
  }
  const float km = 0.125f * LOG2E, kb = -m * LOG2E;
  float sum = 0.f;
#pragma unroll
  for (int blk = 0; blk < 2; ++blk)
    if (blk < blkmax)
#pragma unroll
      for (int r = 0; r < 16; ++r) {
        const float p = __builtin_amdgcn_exp2f(__builtin_fmaf(sv[blk][r], km, kb));
        sv[blk][r] = p;
        sum += p;
      }
  sum += __shfl_xor(sum, 32);
  l += sum;

  // P redistribution (D-layout -> B-operand) + PV
#pragma unroll
  for (int blk = 0; blk < 2; ++blk)
    if (blk < blkmax) {
      uint32_t w[8], xw[8];
#pragma unroll
      for (int g = 0; g < 4; ++g) {
        w[2 * g]     = pk2(sv[blk][4 * g],     sv[blk][4 * g + 1]);
        w[2 * g + 1] = pk2(sv[blk][4 * g + 2], sv[blk][4 * g + 3]);
      }
#pragma unroll
      for (int i = 0; i < 8; ++i)
        xw[i] = (uint32_t)__shfl_xor((int)w[i], 32);
#pragma unroll
      for (int ks = 0; ks < 2; ++ks) {
        union { uint32_t u[4]; bf16x8 v; } pf;
        pf.u[0] = h ? xw[4 * ks + 2] : w[4 * ks];
        pf.u[1] = h ? xw[4 * ks + 3] : w[4 * ks + 1];
        pf.u[2] = h ? w[4 * ks + 2]  : xw[4 * ks];
        pf.u[3] = h ? w[4 * ks + 3]  : xw[4 * ks + 1];
        __builtin_amdgcn_s_setprio(1);
#pragma unroll
        for (int db = 0; db < 2; ++db) {
          const int vrow = db * 32 + c;
          bf16x8 vf = *(const bf16x8*)((const char*)&Vtb[vrow][0] +
                       ((blk * 64 + ks * 32 + h * 16) ^ ((vrow & 7) << 4)));
          oacc[db] = __builtin_amdgcn_mfma_f32_32x32x16_bf16(vf, pf.v, oacc[db], 0, 0, 0);
        }
        __builtin_amdgcn_s_setprio(0);
      }
    }
}

__global__ __launch_bounds__(128) void attn_fwd(
    const bf16* __restrict__ QKV, bf16* __restrict__ O)
{
  __shared__ bf16 Ks[2][64][64];   // K tiles [kv][d], rows XOR-swizzled
  __shared__ bf16 Vt[2][64][64];   // V^T tiles [d][kv], rows XOR-swizzled

  const int pr = blockIdx.x;       // pair index 0..15
  const int bh = blockIdx.y;
  const int bi = bh >> 4, hi = bh & 15;
  const int tid = threadIdx.x, wave = tid >> 6, lane = tid & 63;
  const int c = lane & 31, h = lane >> 5;

  const bf16* qptr = QKV + (size_t)bi * NSEQ * QKVS + hi * HD;
  const bf16* kptr = qptr + DM;
  const bf16* vptr = qptr + 2 * DM;

  // complementary strips (32 q-rows each)
  const int sA = 2 * pr + wave, sB = 63 - sA;
  const int q0A = sA * 32, q0B = sB * 32;

  // Q fragments for both strips (B-operand): k = d = ks*16 + h*8 + e
  bf16x8 qfA[4], qfB[4];
#pragma unroll
  for (int ks = 0; ks < 4; ++ks) {
    qfA[ks] = *(const bf16x8*)(qptr + (size_t)(q0A + c) * QKVS + ks * 16 + h * 8);
    qfB[ks] = *(const bf16x8*)(qptr + (size_t)(q0B + c) * QKVS + ks * 16 + h * 8);
  }

  f32x16 oaccA[2] = {}, oaccB[2] = {};
  float mA = -1e30f, lA = 0.f, mB = -1e30f, lB = 0.f;

  // K staging: 128 threads cover 16 rows x 8 chunks per pass, 4 passes
  const int srow = tid >> 3, sch = tid & 7;
  const int koff = (sch * 16) ^ ((srow & 7) << 4);   // (row+16p)&7 == row&7
  // V staging: thread covers 4 kv rows x 8 d cols (64x64 in one pass)
  const int kvg = (tid & 15) * 4, dg = (tid >> 4) * 8;

  bf16x8 kpre[4], vpre[4];      // prefetch regs (loaded t-1, published top of t+1)

  const int ntil = 32 - pr;     // tiles covering strip B (the larger)

  // prologue: tile0 -> LDS buf0 directly; tile1 -> regs
  {
#pragma unroll
    for (int p = 0; p < 4; ++p)
      kpre[p] = *(const bf16x8*)(kptr + (size_t)(srow + 16 * p) * QKVS + sch * 8);
#pragma unroll
    for (int i = 0; i < 4; ++i)
      vpre[i] = *(const bf16x8*)(vptr + (size_t)(kvg + i) * QKVS + dg);
#pragma unroll
    for (int p = 0; p < 4; ++p)
      *(bf16x8*)((char*)&Ks[0][srow + 16 * p][0] + koff) = kpre[p];
#pragma unroll
    for (int e = 0; e < 8; ++e) {
      const int d = dg + e;
      bf16x4 w; w[0] = vpre[0][e]; w[1] = vpre[1][e];
      w[2] = vpre[2][e]; w[3] = vpre[3][e];
      *(bf16x4*)((char*)&Vt[0][d][0] + ((2 * kvg) ^ ((d & 7) << 4))) = w;
    }
#pragma unroll
    for (int p = 0; p < 4; ++p)
      kpre[p] = *(const bf16x8*)(kptr + (size_t)(64 + srow + 16 * p) * QKVS + sch * 8);
#pragma unroll
    for (int i = 0; i < 4; ++i)
      vpre[i] = *(const bf16x8*)(vptr + (size_t)(64 + kvg + i) * QKVS + dg);
  }
  __syncthreads();

  for (int t = 0; t < ntil; ++t) {
    const int cur = t & 1;
    const int j0 = t * 64;

    // top: publish tile t+1 into the other buffer (its readers finished
    // before the barrier that ended iter t-1)
    if (t + 1 < ntil) {
      const int nb = cur ^ 1;
#pragma unroll
      for (int p = 0; p < 4; ++p)
        *(bf16x8*)((char*)&Ks[nb][srow + 16 * p][0] + koff) = kpre[p];
#pragma unroll
      for (int e = 0; e < 8; ++e) {
        const int d = dg + e;
        bf16x4 w; w[0] = vpre[0][e]; w[1] = vpre[1][e];
        w[2] = vpre[2][e]; w[3] = vpre[3][e];
        *(bf16x4*)((char*)&Vt[nb][d][0] + ((2 * kvg) ^ ((d & 7) << 4))) = w;
      }
    }
    // issue tile t+2 loads (land during next iteration's compute)
    if (t + 2 < ntil) {
      const int jn = j0 + 128;
#pragma unroll
      for (int p = 0; p < 4; ++p)
        kpre[p] = *(const bf16x8*)(kptr + (size_t)(jn + srow + 16 * p) * QKVS + sch * 8);
#pragma unroll
      for (int i = 0; i < 4; ++i)
        vpre[i] = *(const bf16x8*)(vptr + (size_t)(jn + kvg + i) * QKVS + dg);
    }

    // strip B (large) is active on every staged tile
    strip_tile(Ks[cur], Vt[cur], qfB, oaccB, mB, lB, j0, q0B, c, h);
    // strip A (small) active while t <= pr
    if (j0 <= q0A + 31)
      strip_tile(Ks[cur], Vt[cur], qfA, oaccA, mA, lA, j0, q0A, c, h);

    __syncthreads();              // single barrier per tile
  }

  // epilogue: O[q][d] = oacc^T / l   (all lane-local)
#pragma unroll
  for (int sidx = 0; sidx < 2; ++sidx) {
    const f32x16* oacc = sidx ? oaccB : oaccA;
    const float linv = 1.f / (sidx ? lB : lA);
    const int q0 = sidx ? q0B : q0A;
    bf16* obase = O + (size_t)bi * NSEQ * DM + (size_t)hi * HD +
                  (size_t)(q0 + c) * DM;
#pragma unroll
    for (int db = 0; db < 2; ++db)
#pragma unroll
      for (int g = 0; g < 4; ++g) {
        bf16x4 ov;
#pragma unroll
        for (int j = 0; j < 4; ++j) ov[j] = (bf16)(oacc[db][4 * g + j] * linv);
        *(bf16x4*)(obase + db * 32 + 8 * g + 4 * h) = ov;
      }
  }
}

// ---------------- launch ----------------
extern "C" void kernel_launch(void* const* d_in, const int* in_sizes, int n_in,
                              void* d_out, int out_size, void* d_ws, size_t ws_size,
                              hipStream_t stream) {
  const void* x   = d_in[0];   // [2,2048,1024]
  const void* Wq  = d_in[1];   // [1024,1024]
  const void* Wkv = d_in[2];   // [1024,2048]
  const void* Wo  = d_in[3];   // [1024,1024]

  char* ws = (char*)d_ws;
  int*  flag   = (int*)ws;                                      //   4 KiB
  bf16* xb     = (bf16*)(ws + (4ull << 10));                    //   8 MiB
  bf16* WqkvT  = (bf16*)(ws + (4ull << 10) + (8ull  << 20));    //   6 MiB [3072][1024]
  bf16* WoT    = (bf16*)(ws + (4ull << 10) + (14ull << 20));    //   2 MiB [1024][1024]
  bf16* QKVb   = (bf16*)(ws + (4ull << 10) + (16ull << 20));    //  24 MiB [4096][3072]
  bf16* AOb    = xb;  // x dead after projection; reuse

  detect_dtype<<<1, 256, 0, stream>>>((const uint32_t*)x, flag);
  convert_x<<<4194304 / 8 / 256, 256, 0, stream>>>(x, xb, 4194304, flag);

  const dim3 tb(32, 8);
  transpose_conv<<<dim3(1024 / 32, 1024 / 32), tb, 0, stream>>>(Wq,  WqkvT,                1024, 1024, flag);
  transpose_conv<<<dim3(2048 / 32, 1024 / 32), tb, 0, stream>>>(Wkv, WqkvT + 1024 * 1024,  1024, 2048, flag);
  transpose_conv<<<dim3(1024 / 32, 1024 / 32), tb, 0, stream>>>(Wo,  WoT,                  1024, 1024, flag);

  // fused QKV projection: x @ [Wq | Wkv]
  gemm_bt<<<dim3(3072 / 128, 4096 / 128), 256, 0, stream>>>(xb, WqkvT, QKVb, 4096, 3072, 1024, nullptr);

  attn_fwd<<<dim3(16, 32), 128, 0, stream>>>(QKVb, AOb);

  gemm_bt<<<dim3(1024 / 128, 4096 / 128), 256, 0, stream>>>(AOb, WoT, d_out, 4096, 1024, 1024, flag);
}